// Round 8
// baseline (10804.665 us; speedup 1.0000x reference)
//
#include <hip/hip_runtime.h>
#include <hip/hip_bf16.h>

// Problem constants
#define SEQ   4096
#define EMB   256
#define HHID  256      // HH
#define G4    1024     // 4*HH
#define NT    9        // tags
#define TSTART 7
#define TSTOP  8
#define NEGV  (-10000.0f)
#define POISON 0xAAAAAAAAu

// Workspace byte offsets (total ~42.2 MB)
#define WS_XG_F   0u            // 4096*1024 f32 = 16 MB
#define WS_XG_B   16777216u     // 16 MB
#define WS_HF     33554432u     // 4096*256 f32 = 4 MB
#define WS_HB     37748736u     // 4 MB
#define WS_FRAMES 41943040u     // 4096*9 f32 = 147456 B

// Padded LDS index for h: groups of 32 floats padded to 36 (conflict-free
// float4 reads; round-3 verified SQ_LDS_BANK_CONFLICT 2.5e7 -> 0).
#define PIDX(c) ((((c) >> 5) * 36) + ((c) & 31))

// ---------------------------------------------------------------------------
// Kernel 1: x = embed[sentence]; xg = x @ w_ih^T + b_ih + b_hh  (both dirs)
// grid (256, 2), block 256. Gate-interleaved xg layout: xg[s][unit*4+q].
// (byte-identical to round-4/7 passing version)
// ---------------------------------------------------------------------------
__global__ __launch_bounds__(256) void xgate_kernel(
    const int* __restrict__ sentence, const float* __restrict__ embed,
    const float* __restrict__ w_ih_f, const float* __restrict__ b_ih_f,
    const float* __restrict__ b_hh_f,
    const float* __restrict__ w_ih_b, const float* __restrict__ b_ih_b,
    const float* __restrict__ b_hh_b,
    float* __restrict__ xg_f, float* __restrict__ xg_b)
{
    const int st  = blockIdx.x;          // 0..255 (16 s each)
    const int dir = blockIdx.y;
    const float* w  = dir ? w_ih_b : w_ih_f;
    const float* bi = dir ? b_ih_b : b_ih_f;
    const float* bh = dir ? b_hh_b : b_hh_f;
    float* xg = dir ? xg_b : xg_f;
    const int t = threadIdx.x;

    __shared__ float x_t[EMB][16];       // transposed x tile
    for (int sl = 0; sl < 16; ++sl) {
        int s   = st * 16 + sl;
        int tok = sentence[s];
        x_t[t][sl] = embed[(size_t)tok * EMB + t];
    }
    __syncthreads();

    float acc[4][16];
    #pragma unroll
    for (int q = 0; q < 4; ++q)
        #pragma unroll
        for (int sl = 0; sl < 16; ++sl) acc[q][sl] = 0.f;

    const float4* wr0 = (const float4*)(w + (size_t)(t      ) * EMB);
    const float4* wr1 = (const float4*)(w + (size_t)(t + 256) * EMB);
    const float4* wr2 = (const float4*)(w + (size_t)(t + 512) * EMB);
    const float4* wr3 = (const float4*)(w + (size_t)(t + 768) * EMB);
    #pragma unroll 2
    for (int e4 = 0; e4 < EMB / 4; ++e4) {
        float4 w0 = wr0[e4], w1 = wr1[e4], w2 = wr2[e4], w3 = wr3[e4];
        #pragma unroll
        for (int k = 0; k < 4; ++k) {
            float f0 = (k == 0) ? w0.x : (k == 1) ? w0.y : (k == 2) ? w0.z : w0.w;
            float f1 = (k == 0) ? w1.x : (k == 1) ? w1.y : (k == 2) ? w1.z : w1.w;
            float f2 = (k == 0) ? w2.x : (k == 1) ? w2.y : (k == 2) ? w2.z : w2.w;
            float f3 = (k == 0) ? w3.x : (k == 1) ? w3.y : (k == 2) ? w3.z : w3.w;
            int e = e4 * 4 + k;
            #pragma unroll
            for (int sl = 0; sl < 16; ++sl) {
                float xv = x_t[e][sl];
                acc[0][sl] += f0 * xv;
                acc[1][sl] += f1 * xv;
                acc[2][sl] += f2 * xv;
                acc[3][sl] += f3 * xv;
            }
        }
    }

    float bb0 = bi[t      ] + bh[t      ];
    float bb1 = bi[t + 256] + bh[t + 256];
    float bb2 = bi[t + 512] + bh[t + 512];
    float bb3 = bi[t + 768] + bh[t + 768];
    for (int sl = 0; sl < 16; ++sl) {
        float4 val = make_float4(acc[0][sl] + bb0, acc[1][sl] + bb1,
                                 acc[2][sl] + bb2, acc[3][sl] + bb3);
        ((float4*)(xg + (size_t)(st * 16 + sl) * G4))[t] = val;
    }
}

// ---------------------------------------------------------------------------
// Kernel 2: bidirectional LSTM recurrence. 16 blocks x 256 threads.
// blocks 0..7 = forward slices, 8..15 = backward slices.
//
// Round-8 change: WAVE-0 COALESCED POLLING (the round-2 design, never
// actually falsified — r2's failure was a container-level error, not a
// bench verdict). Rationale: measured 4840 cy/step vs ~2200 cy accounted
// (store drain + IC visibility + one load RT + compute); the residual is
// consistent with 224 independent pollers queuing at the TA/fabric and the
// barrier waiting on the slowest straggler. Wave 0 alone sweeps the whole
// 256-word h row as 128 x 8B relaxed agent-scope loads (2/lane, lanes
// consecutive -> coalesced line requests), cutting outstanding poll
// streams ~14x and removing the 224-wide straggler max.
// Safety: identical memory primitives to the r0/r3/r4/r7 passing kernels
// (agent-scope only -> no stale-line trap possible; loop exits only on
// non-poison -> no hang). Each 4B half of an 8B load is independently
// poison-or-final; no tearing at 4B granularity.
//
// Thread t = (unit rb = t>>3 within slice, col-block cb = t&7).
// Weights (128 fp32/thread) in AGPRs; 8-lane shfl_xor reduce; lane cb==0
// does activations + c-state + h store. ONE __syncthreads per step.
// ---------------------------------------------------------------------------
__global__ __launch_bounds__(256, 1) void lstm_kernel(
    const float* __restrict__ xg_f, const float* __restrict__ xg_b,
    const float* __restrict__ w_hh_f, const float* __restrict__ w_hh_b,
    const float* __restrict__ h0, const float* __restrict__ c0,
    float* __restrict__ hf, float* __restrict__ hb)
{
    const int bx    = blockIdx.x;
    const int dir   = bx >> 3;
    const int slice = bx & 7;
    const int t     = threadIdx.x;
    const int cb    = t & 7;          // col block: h cols cb*32 .. cb*32+31
    const int rb    = t >> 3;         // unit within slice (0..31)
    const int unit  = slice * 32 + rb;

    const float* xg   = dir ? xg_b  : xg_f;
    const float* w_hh = dir ? w_hh_b : w_hh_f;
    float* hout = dir ? hb : hf;

    __shared__ float buf[2][288];     // h ping-pong, 36-float padded groups

    // --- weights into AGPRs: wa[q*32+j] = W[q*256+unit][cb*32+j] ---
    float wa[128];
    #pragma unroll
    for (int q = 0; q < 4; ++q) {
        #pragma unroll
        for (int j = 0; j < 32; ++j) {
            float tmp = w_hh[(size_t)(q * HHID + unit) * HHID + cb * 32 + j];
            asm volatile("v_accvgpr_write_b32 %0, %1"
                         : "=a"(wa[q * 32 + j]) : "v"(tmp));
        }
    }

    float c_reg = 0.f;
    if (cb == 0) c_reg = c0[dir * HHID + unit];

    for (int n = 0; n < SEQ; ++n) {
        const int s = dir ? (SEQ - 1 - n) : n;

        // Prefetch xg (independent of h; issues before the poll).
        float4 xgv = make_float4(0.f, 0.f, 0.f, 0.f);
        if (cb == 0) {
            xgv = *(const float4*)(xg + (size_t)s * G4 + 4u * unit);
        }

        // Obtain h_prev into LDS. Step 0: from h0 (all threads).
        // Steps >0: wave 0 sweeps all 256 words as 2 x 8B loads per lane.
        if (n == 0) {
            buf[0][PIDX(t)] = h0[dir * HHID + t];
        } else if (t < 64) {
            const int sp = dir ? (s + 1) : (s - 1);
            const unsigned long long* row =
                (const unsigned long long*)(hout + (size_t)sp * HHID);
            const unsigned long long* p0 = row + t;        // floats 2t,2t+1
            const unsigned long long* p1 = row + 64 + t;   // floats 128+2t,..
            unsigned long long v0 = 0, v1 = 0;
            bool d0 = false, d1 = false;
            do {
                if (!d0) {
                    v0 = __hip_atomic_load(p0, __ATOMIC_RELAXED,
                                           __HIP_MEMORY_SCOPE_AGENT);
                    d0 = ((unsigned)v0 != POISON) &&
                         ((unsigned)(v0 >> 32) != POISON);
                }
                if (!d1) {
                    v1 = __hip_atomic_load(p1, __ATOMIC_RELAXED,
                                           __HIP_MEMORY_SCOPE_AGENT);
                    d1 = ((unsigned)v1 != POISON) &&
                         ((unsigned)(v1 >> 32) != POISON);
                }
            } while (!(d0 && d1));
            const int w0i = 2 * t;          // even -> PIDX(w0i)+1 valid
            const int w1i = 128 + 2 * t;
            buf[n & 1][PIDX(w0i)]     = __uint_as_float((unsigned)v0);
            buf[n & 1][PIDX(w0i) + 1] = __uint_as_float((unsigned)(v0 >> 32));
            buf[n & 1][PIDX(w1i)]     = __uint_as_float((unsigned)v1);
            buf[n & 1][PIDX(w1i) + 1] = __uint_as_float((unsigned)(v1 >> 32));
        }
        __syncthreads();

        // 32-col partial dot for 4 gates (weights from AGPRs, h from LDS)
        float a0 = 0.f, a1 = 0.f, a2 = 0.f, a3 = 0.f;
        const float4* h4 = (const float4*)(&buf[n & 1][cb * 36]);
        #pragma unroll
        for (int j4 = 0; j4 < 8; ++j4) {
            float4 hv = h4[j4];
            #pragma unroll
            for (int k = 0; k < 4; ++k) {
                float hk = (k == 0) ? hv.x : (k == 1) ? hv.y
                         : (k == 2) ? hv.z : hv.w;
                float w0, w1, w2, w3;
                asm volatile("v_accvgpr_read_b32 %0, %1"
                             : "=v"(w0) : "a"(wa[0 * 32 + j4 * 4 + k]));
                asm volatile("v_accvgpr_read_b32 %0, %1"
                             : "=v"(w1) : "a"(wa[1 * 32 + j4 * 4 + k]));
                asm volatile("v_accvgpr_read_b32 %0, %1"
                             : "=v"(w2) : "a"(wa[2 * 32 + j4 * 4 + k]));
                asm volatile("v_accvgpr_read_b32 %0, %1"
                             : "=v"(w3) : "a"(wa[3 * 32 + j4 * 4 + k]));
                a0 += w0 * hk;
                a1 += w1 * hk;
                a2 += w2 * hk;
                a3 += w3 * hk;
            }
        }

        // 8-lane butterfly reduce across col blocks (lanes cb = t&7)
        #pragma unroll
        for (int m = 1; m <= 4; m <<= 1) {
            a0 += __shfl_xor(a0, m);
            a1 += __shfl_xor(a1, m);
            a2 += __shfl_xor(a2, m);
            a3 += __shfl_xor(a3, m);
        }

        // Lane cb==0: activations, state, h store
        if (cb == 0) {
            float gi = a0 + xgv.x;
            float gf = a1 + xgv.y;
            float gg = a2 + xgv.z;
            float go = a3 + xgv.w;
            float iv = 1.f / (1.f + __expf(-gi));
            float fv = 1.f / (1.f + __expf(-gf));
            float gv = 1.f - 2.f / (__expf(2.f * gg) + 1.f);   // tanh
            float ov = 1.f / (1.f + __expf(-go));
            float c  = fv * c_reg + iv * gv;
            c_reg = c;
            float h  = ov * (1.f - 2.f / (__expf(2.f * c) + 1.f));
            unsigned int* dst =
                (unsigned int*)(hout + (size_t)s * HHID) + unit;
            __hip_atomic_store(dst, __float_as_uint(h), __ATOMIC_RELAXED,
                               __HIP_MEMORY_SCOPE_AGENT);
        }
        // No second barrier: next iteration's wave-0 LDS writes target
        // buf[(n+1)&1]; this step's readers use buf[n&1]. The next
        // iteration's single barrier orders buf[(n+1)&1] for its dot.
    }
}

// ---------------------------------------------------------------------------
// Kernel 3: frames = [hf|hb] @ W_out^T + b_out      (4096 x 9)
// ---------------------------------------------------------------------------
__global__ __launch_bounds__(256) void frames_kernel(
    const float* __restrict__ hf, const float* __restrict__ hb,
    const float* __restrict__ W_out, const float* __restrict__ b_out,
    float* __restrict__ frames)
{
    int o = blockIdx.x * 256 + threadIdx.x;
    if (o >= SEQ * NT) return;
    int s = o / NT;
    int j = o - s * NT;
    const float4* a0 = (const float4*)(hf + (size_t)s * HHID);
    const float4* a1 = (const float4*)(hb + (size_t)s * HHID);
    const float4* w0 = (const float4*)(W_out + (size_t)j * 512);
    const float4* w1 = w0 + 64;
    float acc = 0.f;
    #pragma unroll 8
    for (int i = 0; i < 64; ++i) {
        float4 a = a0[i], b = w0[i];
        acc += a.x * b.x + a.y * b.y + a.z * b.z + a.w * b.w;
        float4 c = a1[i], d = w1[i];
        acc += c.x * d.x + c.y * d.y + c.z * d.z + c.w * d.w;
    }
    frames[o] = acc + b_out[j];
}

// ---------------------------------------------------------------------------
// Kernel 4: fused CRF forward + backtrack. ONE wave (64 threads).
// Round-8 change: the 9 alpha broadcasts use READLANE (bitwise-identical
// value; ~VALU latency) instead of __shfl (ds_bpermute, ~LDS latency, 9
// dependent ops opening every one of the 4096 serial steps).
// Forward max tree + first-match argmax + parallel backtrack: unchanged
// from round 7 (passed, absmax 0.0).
// ---------------------------------------------------------------------------
__device__ __forceinline__ unsigned nib_ext(unsigned lo, unsigned hi,
                                            unsigned idx)
{
    unsigned a = (lo >> ((4u * idx) & 31u)) & 15u;
    return (idx < 8u) ? a : (hi & 15u);
}

__device__ __forceinline__ float bcast_lane(float x, int lane)
{
    return __uint_as_float(
        __builtin_amdgcn_readlane(__float_as_uint(x), lane));
}

__global__ __launch_bounds__(64) void crf_kernel(
    const float* __restrict__ frames, const float* __restrict__ trans,
    float* __restrict__ dout)
{
    __shared__ float fr[512 * NT];                 // 18432 B chunk of frames
    __shared__ unsigned char bpl[SEQ * NT];        // 36864 B backpointers
    const int t = threadIdx.x;
    const int tc = (t < NT) ? t : 0;               // clamped lane for fr reads

    float trow[NT];
    #pragma unroll
    for (int i = 0; i < NT; ++i) trow[i] = 0.f;
    if (t < NT) {
        #pragma unroll
        for (int i = 0; i < NT; ++i) trow[i] = trans[i * NT + t];
    }
    float alpha = (t == TSTART) ? 0.f : NEGV;      // lane t holds alpha[t]

    for (int chunk = 0; chunk < 8; ++chunk) {
        // float4 staging (frames base + 18432*chunk both 16B-aligned)
        const float4* src4 = (const float4*)(frames + chunk * 512 * NT);
        float4* dst4 = (float4*)fr;
        for (int idx = t; idx < 512 * NT / 4; idx += 64)
            dst4[idx] = src4[idx];
        __syncthreads();   // single wave: cheap

        for (int sl = 0; sl < 512; ++sl) {
            const int s = chunk * 512 + sl;
            float v[NT];
            #pragma unroll
            for (int i = 0; i < NT; ++i)
                v[i] = bcast_lane(alpha, i) + trow[i]; // readlane broadcast
            // exact max tree (fp max has no rounding -> same mx as chain)
            float m01 = fmaxf(v[0], v[1]), m23 = fmaxf(v[2], v[3]);
            float m45 = fmaxf(v[4], v[5]), m67 = fmaxf(v[6], v[7]);
            float m03 = fmaxf(m01, m23),   m47 = fmaxf(m45, m67);
            float mx  = fmaxf(fmaxf(m03, m47), v[8]);
            // first-match argmax (== jnp.argmax first-occurrence semantics);
            // off the alpha critical path
            int am = 8;
            #pragma unroll
            for (int i = 7; i >= 0; --i)
                if (v[i] == mx) am = i;
            float sum = 0.f;
            #pragma unroll
            for (int i = 0; i < NT; ++i) sum += __expf(v[i] - mx);
            float anew = fr[sl * NT + tc] + mx + __logf(sum);
            if (t < NT) {
                bpl[s * NT + t] = (unsigned char)am;
                alpha = anew;
            }
        }
        __syncthreads();
    }

    // final: fin[j] = alpha[j] + trans[j, STOP]; gather with ALL lanes active
    float fin = NEGV;
    if (t < NT) fin = alpha + trans[t * NT + TSTOP];
    float f[NT];
    #pragma unroll
    for (int j = 0; j < NT; ++j) f[j] = bcast_lane(fin, j);

    // best/score computed by ALL lanes (identical values, same op order);
    // only lane 0 stores the score.
    float mx2 = f[0];
    int best = 0;
    #pragma unroll
    for (int j = 1; j < NT; ++j)
        if (f[j] > mx2) { mx2 = f[j]; best = j; }
    float sum2 = 0.f;
    #pragma unroll
    for (int j = 0; j < NT; ++j) sum2 += __expf(f[j] - mx2);
    if (t == 0) dout[0] = mx2 + __logf(sum2);

    // ---- parallel backtrack (round-7, verified) ---------------------------
    // tag chain: t_{4095}=best; t_s = bpl[(s+1)*NT + t_{s+1}].
    // Lane l owns map rows u = l*64+1 .. l*64+64 (lane 63 row i=63 =
    // identity pad). Rows packed as 9 nibbles. Integer-exact.
    unsigned rlo[64], rhi[64];
    {
        const int base_u = t * 64 + 1;
        #pragma unroll
        for (int i = 0; i < 64; ++i) {
            unsigned lo, hi;
            if (t == 63 && i == 63) {
                lo = 0x76543210u; hi = 8u;           // identity map
            } else {
                const int u = base_u + i;
                lo = 0;
                #pragma unroll
                for (int k = 0; k < 8; ++k)
                    lo |= ((unsigned)bpl[u * NT + k]) << (4 * k);
                hi = (unsigned)bpl[u * NT + 8];
            }
            rlo[i] = lo; rhi[i] = hi;
        }
    }

    // compose segment map G_l = row_0 o row_1 o ... o row_63
    unsigned gm[NT];
    #pragma unroll
    for (int k = 0; k < NT; ++k) gm[k] = (unsigned)k;
    #pragma unroll
    for (int i = 63; i >= 0; --i) {
        #pragma unroll
        for (int k = 0; k < NT; ++k)
            gm[k] = nib_ext(rlo[i], rhi[i], gm[k]);
    }
    unsigned Glo = 0, Ghi = gm[8] & 15u;
    #pragma unroll
    for (int k = 0; k < 8; ++k) Glo |= gm[k] << (4 * k);

    // boundary scan: lane l captures its replay seed E before G_l applies.
    int cur = best;
    int E   = best;
    for (int lx = 63; lx >= 0; --lx) {
        unsigned glo = __shfl(Glo, lx);
        unsigned ghi = __shfl(Ghi, lx);
        if (t == lx) E = cur;
        cur = (int)nib_ext(glo, ghi, (unsigned)cur);
    }

    // replay: lane l writes tags for s = l*64+63 down to l*64.
    unsigned tg = (unsigned)E;
    #pragma unroll
    for (int i = 63; i >= 0; --i) {
        tg = nib_ext(rlo[i], rhi[i], tg);
        dout[1 + t * 64 + i] = (float)tg;
    }
}

// ---------------------------------------------------------------------------
extern "C" void kernel_launch(void* const* d_in, const int* in_sizes, int n_in,
                              void* d_out, int out_size, void* d_ws, size_t ws_size,
                              hipStream_t stream)
{
    const int*   sentence = (const int*)  d_in[0];
    const float* embed    = (const float*)d_in[1];
    const float* w_ih_f   = (const float*)d_in[2];
    const float* w_hh_f   = (const float*)d_in[3];
    const float* b_ih_f   = (const float*)d_in[4];
    const float* b_hh_f   = (const float*)d_in[5];
    const float* w_ih_b   = (const float*)d_in[6];
    const float* w_hh_b   = (const float*)d_in[7];
    const float* b_ih_b   = (const float*)d_in[8];
    const float* b_hh_b   = (const float*)d_in[9];
    const float* h0       = (const float*)d_in[10];
    const float* c0       = (const float*)d_in[11];
    const float* W_out    = (const float*)d_in[12];
    const float* b_out    = (const float*)d_in[13];
    const float* trans    = (const float*)d_in[14];

    float* out = (float*)d_out;
    char*  ws  = (char*)d_ws;

    float* xg_f   = (float*)(ws + WS_XG_F);
    float* xg_b   = (float*)(ws + WS_XG_B);
    float* hf     = (float*)(ws + WS_HF);
    float* hb     = (float*)(ws + WS_HB);
    float* frames = (float*)(ws + WS_FRAMES);

    // hf/hb -> poison ("not yet written" sentinel); contiguous 8 MB memset.
    hipMemsetAsync(hf, 0xAA, 2u * SEQ * HHID * sizeof(float), stream);

    xgate_kernel<<<dim3(256, 2), 256, 0, stream>>>(
        sentence, embed, w_ih_f, b_ih_f, b_hh_f, w_ih_b, b_ih_b, b_hh_b,
        xg_f, xg_b);

    lstm_kernel<<<16, 256, 0, stream>>>(
        xg_f, xg_b, w_hh_f, w_hh_b, h0, c0, hf, hb);

    frames_kernel<<<(SEQ * NT + 255) / 256, 256, 0, stream>>>(
        hf, hb, W_out, b_out, frames);

    crf_kernel<<<1, 64, 0, stream>>>(frames, trans, out);
}

// Round 10
// 9674.213 us; speedup vs baseline: 1.1169x; 1.1169x over previous
//
#include <hip/hip_runtime.h>
#include <hip/hip_bf16.h>

// Problem constants
#define SEQ   4096
#define EMB   256
#define HHID  256      // HH
#define G4    1024     // 4*HH
#define NT    9        // tags
#define TSTART 7
#define TSTOP  8
#define NEGV  (-10000.0f)
#define POISON 0xAAAAAAAAu

// Workspace byte offsets (total ~42.2 MB)
#define WS_XG_F   0u            // 4096*1024 f32 = 16 MB
#define WS_XG_B   16777216u     // 16 MB
#define WS_HF     33554432u     // 4096*256 f32 = 4 MB
#define WS_HB     37748736u     // 4 MB
#define WS_FRAMES 41943040u     // 4096*9 f32 = 147456 B

// Padded LDS index for h: groups of 32 floats padded to 36 (conflict-free
// float4 reads; round-3 verified SQ_LDS_BANK_CONFLICT 2.5e7 -> 0).
#define PIDX(c) ((((c) >> 5) * 36) + ((c) & 31))

// ---------------------------------------------------------------------------
// Kernel 1: x = embed[sentence]; xg = x @ w_ih^T + b_ih + b_hh  (both dirs)
// grid (256, 2), block 256. Gate-interleaved xg layout: xg[s][unit*4+q].
// (byte-identical to round-4/7 passing version)
// ---------------------------------------------------------------------------
__global__ __launch_bounds__(256) void xgate_kernel(
    const int* __restrict__ sentence, const float* __restrict__ embed,
    const float* __restrict__ w_ih_f, const float* __restrict__ b_ih_f,
    const float* __restrict__ b_hh_f,
    const float* __restrict__ w_ih_b, const float* __restrict__ b_ih_b,
    const float* __restrict__ b_hh_b,
    float* __restrict__ xg_f, float* __restrict__ xg_b)
{
    const int st  = blockIdx.x;          // 0..255 (16 s each)
    const int dir = blockIdx.y;
    const float* w  = dir ? w_ih_b : w_ih_f;
    const float* bi = dir ? b_ih_b : b_ih_f;
    const float* bh = dir ? b_hh_b : b_hh_f;
    float* xg = dir ? xg_b : xg_f;
    const int t = threadIdx.x;

    __shared__ float x_t[EMB][16];       // transposed x tile
    for (int sl = 0; sl < 16; ++sl) {
        int s   = st * 16 + sl;
        int tok = sentence[s];
        x_t[t][sl] = embed[(size_t)tok * EMB + t];
    }
    __syncthreads();

    float acc[4][16];
    #pragma unroll
    for (int q = 0; q < 4; ++q)
        #pragma unroll
        for (int sl = 0; sl < 16; ++sl) acc[q][sl] = 0.f;

    const float4* wr0 = (const float4*)(w + (size_t)(t      ) * EMB);
    const float4* wr1 = (const float4*)(w + (size_t)(t + 256) * EMB);
    const float4* wr2 = (const float4*)(w + (size_t)(t + 512) * EMB);
    const float4* wr3 = (const float4*)(w + (size_t)(t + 768) * EMB);
    #pragma unroll 2
    for (int e4 = 0; e4 < EMB / 4; ++e4) {
        float4 w0 = wr0[e4], w1 = wr1[e4], w2 = wr2[e4], w3 = wr3[e4];
        #pragma unroll
        for (int k = 0; k < 4; ++k) {
            float f0 = (k == 0) ? w0.x : (k == 1) ? w0.y : (k == 2) ? w0.z : w0.w;
            float f1 = (k == 0) ? w1.x : (k == 1) ? w1.y : (k == 2) ? w1.z : w1.w;
            float f2 = (k == 0) ? w2.x : (k == 1) ? w2.y : (k == 2) ? w2.z : w2.w;
            float f3 = (k == 0) ? w3.x : (k == 1) ? w3.y : (k == 2) ? w3.z : w3.w;
            int e = e4 * 4 + k;
            #pragma unroll
            for (int sl = 0; sl < 16; ++sl) {
                float xv = x_t[e][sl];
                acc[0][sl] += f0 * xv;
                acc[1][sl] += f1 * xv;
                acc[2][sl] += f2 * xv;
                acc[3][sl] += f3 * xv;
            }
        }
    }

    float bb0 = bi[t      ] + bh[t      ];
    float bb1 = bi[t + 256] + bh[t + 256];
    float bb2 = bi[t + 512] + bh[t + 512];
    float bb3 = bi[t + 768] + bh[t + 768];
    for (int sl = 0; sl < 16; ++sl) {
        float4 val = make_float4(acc[0][sl] + bb0, acc[1][sl] + bb1,
                                 acc[2][sl] + bb2, acc[3][sl] + bb3);
        ((float4*)(xg + (size_t)(st * 16 + sl) * G4))[t] = val;
    }
}

// ---------------------------------------------------------------------------
// Kernel 2: bidirectional LSTM recurrence. 16 blocks x 256 threads.
// EXACT round-7 passing version (per-thread 4B agent-scope exchange with
// staggered quad-slot poll — best measured at 8260-8290 us). Closed:
// r1/r5/r6 (sc0 fast path = stale-line trap), r8 (wave-0 coalesced poll =
// +1130 us), r3/r4 (poll scheduling ~null). The ~2us/step is the
// device-coherence-point store->visibility->load round trip. Do not touch.
// ---------------------------------------------------------------------------
__global__ __launch_bounds__(256, 1) void lstm_kernel(
    const float* __restrict__ xg_f, const float* __restrict__ xg_b,
    const float* __restrict__ w_hh_f, const float* __restrict__ w_hh_b,
    const float* __restrict__ h0, const float* __restrict__ c0,
    float* __restrict__ hf, float* __restrict__ hb)
{
    const int bx    = blockIdx.x;
    const int dir   = bx >> 3;
    const int slice = bx & 7;
    const int t     = threadIdx.x;
    const int cb    = t & 7;          // col block: h cols cb*32 .. cb*32+31
    const int rb    = t >> 3;         // unit within slice (0..31)
    const int unit  = slice * 32 + rb;

    const float* xg   = dir ? xg_b  : xg_f;
    const float* w_hh = dir ? w_hh_b : w_hh_f;
    float* hout = dir ? hb : hf;

    __shared__ float buf[2][288];     // h ping-pong, 36-float padded groups

    // --- weights into AGPRs: wa[q*32+j] = W[q*256+unit][cb*32+j] ---
    float wa[128];
    #pragma unroll
    for (int q = 0; q < 4; ++q) {
        #pragma unroll
        for (int j = 0; j < 32; ++j) {
            float tmp = w_hh[(size_t)(q * HHID + unit) * HHID + cb * 32 + j];
            asm volatile("v_accvgpr_write_b32 %0, %1"
                         : "=a"(wa[q * 32 + j]) : "v"(tmp));
        }
    }

    float c_reg = 0.f;
    if (cb == 0) c_reg = c0[dir * HHID + unit];

    const bool own = (t >= slice * 32) && (t < slice * 32 + 32);

    for (int n = 0; n < SEQ; ++n) {
        const int s = dir ? (SEQ - 1 - n) : n;

        // Prefetch xg (independent of h; issues before the poll).
        float4 xgv = make_float4(0.f, 0.f, 0.f, 0.f);
        if (cb == 0) {
            xgv = *(const float4*)(xg + (size_t)s * G4 + 4u * unit);
        }

        // Obtain h_prev word t into LDS (own 32 words arrive via local path)
        if (n == 0) {
            buf[0][PIDX(t)] = h0[dir * HHID + t];
        } else if (!own) {
            const int sp = dir ? (s + 1) : (s - 1);
            const unsigned int* src =
                (const unsigned int*)(hout + (size_t)sp * HHID) + t;
            unsigned v = __hip_atomic_load(src, __ATOMIC_RELAXED,
                                           __HIP_MEMORY_SCOPE_AGENT);
            if (v == POISON) {
                unsigned q0, q1, q2, q3;
                q0 = __hip_atomic_load(src, __ATOMIC_RELAXED,
                                       __HIP_MEMORY_SCOPE_AGENT);
                __builtin_amdgcn_s_sleep(2);
                q1 = __hip_atomic_load(src, __ATOMIC_RELAXED,
                                       __HIP_MEMORY_SCOPE_AGENT);
                __builtin_amdgcn_s_sleep(2);
                q2 = __hip_atomic_load(src, __ATOMIC_RELAXED,
                                       __HIP_MEMORY_SCOPE_AGENT);
                __builtin_amdgcn_s_sleep(2);
                q3 = __hip_atomic_load(src, __ATOMIC_RELAXED,
                                       __HIP_MEMORY_SCOPE_AGENT);
                for (;;) {
                    if (q0 != POISON) { v = q0; break; }
                    q0 = __hip_atomic_load(src, __ATOMIC_RELAXED,
                                           __HIP_MEMORY_SCOPE_AGENT);
                    if (q1 != POISON) { v = q1; break; }
                    q1 = __hip_atomic_load(src, __ATOMIC_RELAXED,
                                           __HIP_MEMORY_SCOPE_AGENT);
                    if (q2 != POISON) { v = q2; break; }
                    q2 = __hip_atomic_load(src, __ATOMIC_RELAXED,
                                           __HIP_MEMORY_SCOPE_AGENT);
                    if (q3 != POISON) { v = q3; break; }
                    q3 = __hip_atomic_load(src, __ATOMIC_RELAXED,
                                           __HIP_MEMORY_SCOPE_AGENT);
                }
            }
            buf[n & 1][PIDX(t)] = __uint_as_float(v);
        }
        __syncthreads();

        // 32-col partial dot for 4 gates (weights from AGPRs, h from LDS)
        float a0 = 0.f, a1 = 0.f, a2 = 0.f, a3 = 0.f;
        const float4* h4 = (const float4*)(&buf[n & 1][cb * 36]);
        #pragma unroll
        for (int j4 = 0; j4 < 8; ++j4) {
            float4 hv = h4[j4];
            #pragma unroll
            for (int k = 0; k < 4; ++k) {
                float hk = (k == 0) ? hv.x : (k == 1) ? hv.y
                         : (k == 2) ? hv.z : hv.w;
                float w0, w1, w2, w3;
                asm volatile("v_accvgpr_read_b32 %0, %1"
                             : "=v"(w0) : "a"(wa[0 * 32 + j4 * 4 + k]));
                asm volatile("v_accvgpr_read_b32 %0, %1"
                             : "=v"(w1) : "a"(wa[1 * 32 + j4 * 4 + k]));
                asm volatile("v_accvgpr_read_b32 %0, %1"
                             : "=v"(w2) : "a"(wa[2 * 32 + j4 * 4 + k]));
                asm volatile("v_accvgpr_read_b32 %0, %1"
                             : "=v"(w3) : "a"(wa[3 * 32 + j4 * 4 + k]));
                a0 += w0 * hk;
                a1 += w1 * hk;
                a2 += w2 * hk;
                a3 += w3 * hk;
            }
        }

        // 8-lane butterfly reduce across col blocks (lanes cb = t&7)
        #pragma unroll
        for (int m = 1; m <= 4; m <<= 1) {
            a0 += __shfl_xor(a0, m);
            a1 += __shfl_xor(a1, m);
            a2 += __shfl_xor(a2, m);
            a3 += __shfl_xor(a3, m);
        }

        // Lane cb==0: activations, state, h store
        if (cb == 0) {
            float gi = a0 + xgv.x;
            float gf = a1 + xgv.y;
            float gg = a2 + xgv.z;
            float go = a3 + xgv.w;
            float iv = 1.f / (1.f + __expf(-gi));
            float fv = 1.f / (1.f + __expf(-gf));
            float gv = 1.f - 2.f / (__expf(2.f * gg) + 1.f);   // tanh
            float ov = 1.f / (1.f + __expf(-go));
            float c  = fv * c_reg + iv * gv;
            c_reg = c;
            float h  = ov * (1.f - 2.f / (__expf(2.f * c) + 1.f));
            unsigned int* dst =
                (unsigned int*)(hout + (size_t)s * HHID) + unit;
            __hip_atomic_store(dst, __float_as_uint(h), __ATOMIC_RELAXED,
                               __HIP_MEMORY_SCOPE_AGENT);
            buf[(n + 1) & 1][PIDX(unit)] = h;   // local shortcut, next step
        }
    }
}

// ---------------------------------------------------------------------------
// Kernel 3: frames = [hf|hb] @ W_out^T + b_out      (4096 x 9)
// ---------------------------------------------------------------------------
__global__ __launch_bounds__(256) void frames_kernel(
    const float* __restrict__ hf, const float* __restrict__ hb,
    const float* __restrict__ W_out, const float* __restrict__ b_out,
    float* __restrict__ frames)
{
    int o = blockIdx.x * 256 + threadIdx.x;
    if (o >= SEQ * NT) return;
    int s = o / NT;
    int j = o - s * NT;
    const float4* a0 = (const float4*)(hf + (size_t)s * HHID);
    const float4* a1 = (const float4*)(hb + (size_t)s * HHID);
    const float4* w0 = (const float4*)(W_out + (size_t)j * 512);
    const float4* w1 = w0 + 64;
    float acc = 0.f;
    #pragma unroll 8
    for (int i = 0; i < 64; ++i) {
        float4 a = a0[i], b = w0[i];
        acc += a.x * b.x + a.y * b.y + a.z * b.z + a.w * b.w;
        float4 c = a1[i], d = w1[i];
        acc += c.x * d.x + c.y * d.y + c.z * d.z + c.w * d.w;
    }
    frames[o] = acc + b_out[j];
}

// ---------------------------------------------------------------------------
// Kernel 4: fused CRF forward + backtrack. ONE wave (64 threads).
// Round-9 change (resubmitted; r9 bench was an infra failure, not a
// verdict): the emission read fr[sl*NT+tc] is PREFETCHED one step ahead
// into a register (frn), taking the ~120cy LDS latency off the serial
// alpha chain; fm = frv + mx is pre-added while the exps run so the final
// dependent op after log is one add. Exp/sum op ORDER unchanged (linear
// sum) -> bit-identical to r7/r8 (absmax 0.0).
// readlane broadcast (r8) + max tree + first-match argmax (r7) +
// parallel backtrack (r7) retained.
// ---------------------------------------------------------------------------
__device__ __forceinline__ unsigned nib_ext(unsigned lo, unsigned hi,
                                            unsigned idx)
{
    unsigned a = (lo >> ((4u * idx) & 31u)) & 15u;
    return (idx < 8u) ? a : (hi & 15u);
}

__device__ __forceinline__ float bcast_lane(float x, int lane)
{
    return __uint_as_float(
        __builtin_amdgcn_readlane(__float_as_uint(x), lane));
}

__global__ __launch_bounds__(64) void crf_kernel(
    const float* __restrict__ frames, const float* __restrict__ trans,
    float* __restrict__ dout)
{
    __shared__ float fr[512 * NT + 16];            // +pad for prefetch-past-end
    __shared__ unsigned char bpl[SEQ * NT];        // 36864 B backpointers
    const int t = threadIdx.x;
    const int tc = (t < NT) ? t : 0;               // clamped lane for fr reads

    float trow[NT];
    #pragma unroll
    for (int i = 0; i < NT; ++i) trow[i] = 0.f;
    if (t < NT) {
        #pragma unroll
        for (int i = 0; i < NT; ++i) trow[i] = trans[i * NT + t];
    }
    float alpha = (t == TSTART) ? 0.f : NEGV;      // lane t holds alpha[t]

    for (int chunk = 0; chunk < 8; ++chunk) {
        // float4 staging (frames base + 18432*chunk both 16B-aligned)
        const float4* src4 = (const float4*)(frames + chunk * 512 * NT);
        float4* dst4 = (float4*)fr;
        for (int idx = t; idx < 512 * NT / 4; idx += 64)
            dst4[idx] = src4[idx];
        __syncthreads();   // single wave: cheap

        float frv = fr[tc];                        // prefetch seed for sl=0
        for (int sl = 0; sl < 512; ++sl) {
            const int s = chunk * 512 + sl;
            float frn = fr[(sl + 1) * NT + tc];    // prefetch next (off-chain)
            float v[NT];
            #pragma unroll
            for (int i = 0; i < NT; ++i)
                v[i] = bcast_lane(alpha, i) + trow[i]; // readlane broadcast
            // exact max tree (fp max has no rounding -> same mx as chain)
            float m01 = fmaxf(v[0], v[1]), m23 = fmaxf(v[2], v[3]);
            float m45 = fmaxf(v[4], v[5]), m67 = fmaxf(v[6], v[7]);
            float m03 = fmaxf(m01, m23),   m47 = fmaxf(m45, m67);
            float mx  = fmaxf(fmaxf(m03, m47), v[8]);
            float fm  = frv + mx;                  // pre-add while exps run
            // first-match argmax (== jnp.argmax first-occurrence semantics);
            // off the alpha critical path
            int am = 8;
            #pragma unroll
            for (int i = 7; i >= 0; --i)
                if (v[i] == mx) am = i;
            float sum = 0.f;                       // LINEAR order (bit-exact)
            #pragma unroll
            for (int i = 0; i < NT; ++i) sum += __expf(v[i] - mx);
            float anew = fm + __logf(sum);
            if (t < NT) {
                bpl[s * NT + t] = (unsigned char)am;
                alpha = anew;
            }
            frv = frn;
        }
        __syncthreads();
    }

    // final: fin[j] = alpha[j] + trans[j, STOP]; gather with ALL lanes active
    float fin = NEGV;
    if (t < NT) fin = alpha + trans[t * NT + TSTOP];
    float f[NT];
    #pragma unroll
    for (int j = 0; j < NT; ++j) f[j] = bcast_lane(fin, j);

    // best/score computed by ALL lanes (identical values, same op order);
    // only lane 0 stores the score.
    float mx2 = f[0];
    int best = 0;
    #pragma unroll
    for (int j = 1; j < NT; ++j)
        if (f[j] > mx2) { mx2 = f[j]; best = j; }
    float sum2 = 0.f;
    #pragma unroll
    for (int j = 0; j < NT; ++j) sum2 += __expf(f[j] - mx2);
    if (t == 0) dout[0] = mx2 + __logf(sum2);

    // ---- parallel backtrack (round-7, verified) ---------------------------
    // tag chain: t_{4095}=best; t_s = bpl[(s+1)*NT + t_{s+1}].
    // Lane l owns map rows u = l*64+1 .. l*64+64 (lane 63 row i=63 =
    // identity pad). Rows packed as 9 nibbles. Integer-exact.
    unsigned rlo[64], rhi[64];
    {
        const int base_u = t * 64 + 1;
        #pragma unroll
        for (int i = 0; i < 64; ++i) {
            unsigned lo, hi;
            if (t == 63 && i == 63) {
                lo = 0x76543210u; hi = 8u;           // identity map
            } else {
                const int u = base_u + i;
                lo = 0;
                #pragma unroll
                for (int k = 0; k < 8; ++k)
                    lo |= ((unsigned)bpl[u * NT + k]) << (4 * k);
                hi = (unsigned)bpl[u * NT + 8];
            }
            rlo[i] = lo; rhi[i] = hi;
        }
    }

    // compose segment map G_l = row_0 o row_1 o ... o row_63
    unsigned gm[NT];
    #pragma unroll
    for (int k = 0; k < NT; ++k) gm[k] = (unsigned)k;
    #pragma unroll
    for (int i = 63; i >= 0; --i) {
        #pragma unroll
        for (int k = 0; k < NT; ++k)
            gm[k] = nib_ext(rlo[i], rhi[i], gm[k]);
    }
    unsigned Glo = 0, Ghi = gm[8] & 15u;
    #pragma unroll
    for (int k = 0; k < 8; ++k) Glo |= gm[k] << (4 * k);

    // boundary scan: lane l captures its replay seed E before G_l applies.
    int cur = best;
    int E   = best;
    for (int lx = 63; lx >= 0; --lx) {
        unsigned glo = __shfl(Glo, lx);
        unsigned ghi = __shfl(Ghi, lx);
        if (t == lx) E = cur;
        cur = (int)nib_ext(glo, ghi, (unsigned)cur);
    }

    // replay: lane l writes tags for s = l*64+63 down to l*64.
    unsigned tg = (unsigned)E;
    #pragma unroll
    for (int i = 63; i >= 0; --i) {
        tg = nib_ext(rlo[i], rhi[i], tg);
        dout[1 + t * 64 + i] = (float)tg;
    }
}

// ---------------------------------------------------------------------------
extern "C" void kernel_launch(void* const* d_in, const int* in_sizes, int n_in,
                              void* d_out, int out_size, void* d_ws, size_t ws_size,
                              hipStream_t stream)
{
    const int*   sentence = (const int*)  d_in[0];
    const float* embed    = (const float*)d_in[1];
    const float* w_ih_f   = (const float*)d_in[2];
    const float* w_hh_f   = (const float*)d_in[3];
    const float* b_ih_f   = (const float*)d_in[4];
    const float* b_hh_f   = (const float*)d_in[5];
    const float* w_ih_b   = (const float*)d_in[6];
    const float* w_hh_b   = (const float*)d_in[7];
    const float* b_ih_b   = (const float*)d_in[8];
    const float* b_hh_b   = (const float*)d_in[9];
    const float* h0       = (const float*)d_in[10];
    const float* c0       = (const float*)d_in[11];
    const float* W_out    = (const float*)d_in[12];
    const float* b_out    = (const float*)d_in[13];
    const float* trans    = (const float*)d_in[14];

    float* out = (float*)d_out;
    char*  ws  = (char*)d_ws;

    float* xg_f   = (float*)(ws + WS_XG_F);
    float* xg_b   = (float*)(ws + WS_XG_B);
    float* hf     = (float*)(ws + WS_HF);
    float* hb     = (float*)(ws + WS_HB);
    float* frames = (float*)(ws + WS_FRAMES);

    // hf/hb -> poison ("not yet written" sentinel); contiguous 8 MB memset.
    hipMemsetAsync(hf, 0xAA, 2u * SEQ * HHID * sizeof(float), stream);

    xgate_kernel<<<dim3(256, 2), 256, 0, stream>>>(
        sentence, embed, w_ih_f, b_ih_f, b_hh_f, w_ih_b, b_ih_b, b_hh_b,
        xg_f, xg_b);

    lstm_kernel<<<16, 256, 0, stream>>>(
        xg_f, xg_b, w_hh_f, w_hh_b, h0, c0, hf, hb);

    frames_kernel<<<(SEQ * NT + 255) / 256, 256, 0, stream>>>(
        hf, hb, W_out, b_out, frames);

    crf_kernel<<<1, 64, 0, stream>>>(frames, trans, out);
}

// Round 11
// 9569.170 us; speedup vs baseline: 1.1291x; 1.0110x over previous
//
#include <hip/hip_runtime.h>
#include <hip/hip_bf16.h>

// Problem constants
#define SEQ   4096
#define EMB   256
#define HHID  256      // HH
#define G4    1024     // 4*HH
#define NT    9        // tags
#define TSTART 7
#define TSTOP  8
#define NEGV  (-10000.0f)
#define POISON 0xAAAAAAAAu

// Workspace byte offsets (total ~42.2 MB)
#define WS_XG_F   0u            // 4096*1024 f32 = 16 MB
#define WS_XG_B   16777216u     // 16 MB
#define WS_HF     33554432u     // 4096*256 f32 = 4 MB
#define WS_HB     37748736u     // 4 MB
#define WS_FRAMES 41943040u     // 4096*9 f32 = 147456 B

// Padded LDS index for h: groups of 32 floats padded to 36 (conflict-free
// float4 reads; round-3 verified SQ_LDS_BANK_CONFLICT 2.5e7 -> 0).
#define PIDX(c) ((((c) >> 5) * 36) + ((c) & 31))

// ---------------------------------------------------------------------------
// Kernel 1: x = embed[sentence]; xg = x @ w_ih^T + b_ih + b_hh  (both dirs)
// grid (256, 2), block 256. Gate-interleaved xg layout: xg[s][unit*4+q].
// Round-11: also poisons hf/hb (8 MB, contiguous at hf) — replaces the
// host-side hipMemsetAsync dispatch. 131072 threads x 64 B = exact cover;
// stream order (xgate completes before lstm) guarantees visibility.
// ---------------------------------------------------------------------------
__global__ __launch_bounds__(256) void xgate_kernel(
    const int* __restrict__ sentence, const float* __restrict__ embed,
    const float* __restrict__ w_ih_f, const float* __restrict__ b_ih_f,
    const float* __restrict__ b_hh_f,
    const float* __restrict__ w_ih_b, const float* __restrict__ b_ih_b,
    const float* __restrict__ b_hh_b,
    float* __restrict__ xg_f, float* __restrict__ xg_b,
    float* __restrict__ hf_poison)
{
    const int st  = blockIdx.x;          // 0..255 (16 s each)
    const int dir = blockIdx.y;
    const float* w  = dir ? w_ih_b : w_ih_f;
    const float* bi = dir ? b_ih_b : b_ih_f;
    const float* bh = dir ? b_hh_b : b_hh_f;
    float* xg = dir ? xg_b : xg_f;
    const int t = threadIdx.x;

    // Poison hf/hb: thread pid writes 4 consecutive float4s (64 B).
    {
        const unsigned pid = (blockIdx.y * 256u + blockIdx.x) * 256u + t;
        float4* p = (float4*)hf_poison + (size_t)pid * 4u;
        const float pf = __uint_as_float(POISON);
        const float4 pv = make_float4(pf, pf, pf, pf);
        p[0] = pv; p[1] = pv; p[2] = pv; p[3] = pv;
    }

    __shared__ float x_t[EMB][16];       // transposed x tile
    for (int sl = 0; sl < 16; ++sl) {
        int s   = st * 16 + sl;
        int tok = sentence[s];
        x_t[t][sl] = embed[(size_t)tok * EMB + t];
    }
    __syncthreads();

    float acc[4][16];
    #pragma unroll
    for (int q = 0; q < 4; ++q)
        #pragma unroll
        for (int sl = 0; sl < 16; ++sl) acc[q][sl] = 0.f;

    const float4* wr0 = (const float4*)(w + (size_t)(t      ) * EMB);
    const float4* wr1 = (const float4*)(w + (size_t)(t + 256) * EMB);
    const float4* wr2 = (const float4*)(w + (size_t)(t + 512) * EMB);
    const float4* wr3 = (const float4*)(w + (size_t)(t + 768) * EMB);
    #pragma unroll 2
    for (int e4 = 0; e4 < EMB / 4; ++e4) {
        float4 w0 = wr0[e4], w1 = wr1[e4], w2 = wr2[e4], w3 = wr3[e4];
        #pragma unroll
        for (int k = 0; k < 4; ++k) {
            float f0 = (k == 0) ? w0.x : (k == 1) ? w0.y : (k == 2) ? w0.z : w0.w;
            float f1 = (k == 0) ? w1.x : (k == 1) ? w1.y : (k == 2) ? w1.z : w1.w;
            float f2 = (k == 0) ? w2.x : (k == 1) ? w2.y : (k == 2) ? w2.z : w2.w;
            float f3 = (k == 0) ? w3.x : (k == 1) ? w3.y : (k == 2) ? w3.z : w3.w;
            int e = e4 * 4 + k;
            #pragma unroll
            for (int sl = 0; sl < 16; ++sl) {
                float xv = x_t[e][sl];
                acc[0][sl] += f0 * xv;
                acc[1][sl] += f1 * xv;
                acc[2][sl] += f2 * xv;
                acc[3][sl] += f3 * xv;
            }
        }
    }

    float bb0 = bi[t      ] + bh[t      ];
    float bb1 = bi[t + 256] + bh[t + 256];
    float bb2 = bi[t + 512] + bh[t + 512];
    float bb3 = bi[t + 768] + bh[t + 768];
    for (int sl = 0; sl < 16; ++sl) {
        float4 val = make_float4(acc[0][sl] + bb0, acc[1][sl] + bb1,
                                 acc[2][sl] + bb2, acc[3][sl] + bb3);
        ((float4*)(xg + (size_t)(st * 16 + sl) * G4))[t] = val;
    }
}

// ---------------------------------------------------------------------------
// Kernel 2: bidirectional LSTM recurrence. 16 blocks x 256 threads.
// EXACT round-7 passing version (per-thread 4B agent-scope exchange with
// staggered quad-slot poll — best measured at 8260-8290 us). Closed:
// r1/r5/r6 (sc0 fast path = stale-line trap), r8 (wave-0 coalesced poll =
// +1130 us), r3/r4 (poll scheduling ~null). The ~2us/step is the
// device-coherence-point store->visibility->load round trip. Do not touch.
// ---------------------------------------------------------------------------
__global__ __launch_bounds__(256, 1) void lstm_kernel(
    const float* __restrict__ xg_f, const float* __restrict__ xg_b,
    const float* __restrict__ w_hh_f, const float* __restrict__ w_hh_b,
    const float* __restrict__ h0, const float* __restrict__ c0,
    float* __restrict__ hf, float* __restrict__ hb)
{
    const int bx    = blockIdx.x;
    const int dir   = bx >> 3;
    const int slice = bx & 7;
    const int t     = threadIdx.x;
    const int cb    = t & 7;          // col block: h cols cb*32 .. cb*32+31
    const int rb    = t >> 3;         // unit within slice (0..31)
    const int unit  = slice * 32 + rb;

    const float* xg   = dir ? xg_b  : xg_f;
    const float* w_hh = dir ? w_hh_b : w_hh_f;
    float* hout = dir ? hb : hf;

    __shared__ float buf[2][288];     // h ping-pong, 36-float padded groups

    // --- weights into AGPRs: wa[q*32+j] = W[q*256+unit][cb*32+j] ---
    float wa[128];
    #pragma unroll
    for (int q = 0; q < 4; ++q) {
        #pragma unroll
        for (int j = 0; j < 32; ++j) {
            float tmp = w_hh[(size_t)(q * HHID + unit) * HHID + cb * 32 + j];
            asm volatile("v_accvgpr_write_b32 %0, %1"
                         : "=a"(wa[q * 32 + j]) : "v"(tmp));
        }
    }

    float c_reg = 0.f;
    if (cb == 0) c_reg = c0[dir * HHID + unit];

    const bool own = (t >= slice * 32) && (t < slice * 32 + 32);

    for (int n = 0; n < SEQ; ++n) {
        const int s = dir ? (SEQ - 1 - n) : n;

        // Prefetch xg (independent of h; issues before the poll).
        float4 xgv = make_float4(0.f, 0.f, 0.f, 0.f);
        if (cb == 0) {
            xgv = *(const float4*)(xg + (size_t)s * G4 + 4u * unit);
        }

        // Obtain h_prev word t into LDS (own 32 words arrive via local path)
        if (n == 0) {
            buf[0][PIDX(t)] = h0[dir * HHID + t];
        } else if (!own) {
            const int sp = dir ? (s + 1) : (s - 1);
            const unsigned int* src =
                (const unsigned int*)(hout + (size_t)sp * HHID) + t;
            unsigned v = __hip_atomic_load(src, __ATOMIC_RELAXED,
                                           __HIP_MEMORY_SCOPE_AGENT);
            if (v == POISON) {
                unsigned q0, q1, q2, q3;
                q0 = __hip_atomic_load(src, __ATOMIC_RELAXED,
                                       __HIP_MEMORY_SCOPE_AGENT);
                __builtin_amdgcn_s_sleep(2);
                q1 = __hip_atomic_load(src, __ATOMIC_RELAXED,
                                       __HIP_MEMORY_SCOPE_AGENT);
                __builtin_amdgcn_s_sleep(2);
                q2 = __hip_atomic_load(src, __ATOMIC_RELAXED,
                                       __HIP_MEMORY_SCOPE_AGENT);
                __builtin_amdgcn_s_sleep(2);
                q3 = __hip_atomic_load(src, __ATOMIC_RELAXED,
                                       __HIP_MEMORY_SCOPE_AGENT);
                for (;;) {
                    if (q0 != POISON) { v = q0; break; }
                    q0 = __hip_atomic_load(src, __ATOMIC_RELAXED,
                                           __HIP_MEMORY_SCOPE_AGENT);
                    if (q1 != POISON) { v = q1; break; }
                    q1 = __hip_atomic_load(src, __ATOMIC_RELAXED,
                                           __HIP_MEMORY_SCOPE_AGENT);
                    if (q2 != POISON) { v = q2; break; }
                    q2 = __hip_atomic_load(src, __ATOMIC_RELAXED,
                                           __HIP_MEMORY_SCOPE_AGENT);
                    if (q3 != POISON) { v = q3; break; }
                    q3 = __hip_atomic_load(src, __ATOMIC_RELAXED,
                                           __HIP_MEMORY_SCOPE_AGENT);
                }
            }
            buf[n & 1][PIDX(t)] = __uint_as_float(v);
        }
        __syncthreads();

        // 32-col partial dot for 4 gates (weights from AGPRs, h from LDS)
        float a0 = 0.f, a1 = 0.f, a2 = 0.f, a3 = 0.f;
        const float4* h4 = (const float4*)(&buf[n & 1][cb * 36]);
        #pragma unroll
        for (int j4 = 0; j4 < 8; ++j4) {
            float4 hv = h4[j4];
            #pragma unroll
            for (int k = 0; k < 4; ++k) {
                float hk = (k == 0) ? hv.x : (k == 1) ? hv.y
                         : (k == 2) ? hv.z : hv.w;
                float w0, w1, w2, w3;
                asm volatile("v_accvgpr_read_b32 %0, %1"
                             : "=v"(w0) : "a"(wa[0 * 32 + j4 * 4 + k]));
                asm volatile("v_accvgpr_read_b32 %0, %1"
                             : "=v"(w1) : "a"(wa[1 * 32 + j4 * 4 + k]));
                asm volatile("v_accvgpr_read_b32 %0, %1"
                             : "=v"(w2) : "a"(wa[2 * 32 + j4 * 4 + k]));
                asm volatile("v_accvgpr_read_b32 %0, %1"
                             : "=v"(w3) : "a"(wa[3 * 32 + j4 * 4 + k]));
                a0 += w0 * hk;
                a1 += w1 * hk;
                a2 += w2 * hk;
                a3 += w3 * hk;
            }
        }

        // 8-lane butterfly reduce across col blocks (lanes cb = t&7)
        #pragma unroll
        for (int m = 1; m <= 4; m <<= 1) {
            a0 += __shfl_xor(a0, m);
            a1 += __shfl_xor(a1, m);
            a2 += __shfl_xor(a2, m);
            a3 += __shfl_xor(a3, m);
        }

        // Lane cb==0: activations, state, h store
        if (cb == 0) {
            float gi = a0 + xgv.x;
            float gf = a1 + xgv.y;
            float gg = a2 + xgv.z;
            float go = a3 + xgv.w;
            float iv = 1.f / (1.f + __expf(-gi));
            float fv = 1.f / (1.f + __expf(-gf));
            float gv = 1.f - 2.f / (__expf(2.f * gg) + 1.f);   // tanh
            float ov = 1.f / (1.f + __expf(-go));
            float c  = fv * c_reg + iv * gv;
            c_reg = c;
            float h  = ov * (1.f - 2.f / (__expf(2.f * c) + 1.f));
            unsigned int* dst =
                (unsigned int*)(hout + (size_t)s * HHID) + unit;
            __hip_atomic_store(dst, __float_as_uint(h), __ATOMIC_RELAXED,
                               __HIP_MEMORY_SCOPE_AGENT);
            buf[(n + 1) & 1][PIDX(unit)] = h;   // local shortcut, next step
        }
    }
}

// ---------------------------------------------------------------------------
// Kernel 3: frames = [hf|hb] @ W_out^T + b_out      (4096 x 9)
// ---------------------------------------------------------------------------
__global__ __launch_bounds__(256) void frames_kernel(
    const float* __restrict__ hf, const float* __restrict__ hb,
    const float* __restrict__ W_out, const float* __restrict__ b_out,
    float* __restrict__ frames)
{
    int o = blockIdx.x * 256 + threadIdx.x;
    if (o >= SEQ * NT) return;
    int s = o / NT;
    int j = o - s * NT;
    const float4* a0 = (const float4*)(hf + (size_t)s * HHID);
    const float4* a1 = (const float4*)(hb + (size_t)s * HHID);
    const float4* w0 = (const float4*)(W_out + (size_t)j * 512);
    const float4* w1 = w0 + 64;
    float acc = 0.f;
    #pragma unroll 8
    for (int i = 0; i < 64; ++i) {
        float4 a = a0[i], b = w0[i];
        acc += a.x * b.x + a.y * b.y + a.z * b.z + a.w * b.w;
        float4 c = a1[i], d = w1[i];
        acc += c.x * d.x + c.y * d.y + c.z * d.z + c.w * d.w;
    }
    frames[o] = acc + b_out[j];
}

// ---------------------------------------------------------------------------
// Kernel 4: fused CRF forward + backtrack. ONE wave (64 threads).
// Round-11 changes (bitwise-exact):
//  (a) max tree via 3-way fmaxf nesting -> clang fuses to 4 x v_max3_f32
//      (fp max is exact under any association -> identical mx).
//  (b) #pragma unroll 4 on the serial loop: index arithmetic folds to
//      constants; scheduler overlaps step n's off-chain tail (argmax,
//      bpl store) with step n+1's broadcast.
// readlane broadcast (r8), emission prefetch (r10), first-match argmax +
// parallel backtrack (r7) retained. Exp/sum op order untouched.
// ---------------------------------------------------------------------------
__device__ __forceinline__ unsigned nib_ext(unsigned lo, unsigned hi,
                                            unsigned idx)
{
    unsigned a = (lo >> ((4u * idx) & 31u)) & 15u;
    return (idx < 8u) ? a : (hi & 15u);
}

__device__ __forceinline__ float bcast_lane(float x, int lane)
{
    return __uint_as_float(
        __builtin_amdgcn_readlane(__float_as_uint(x), lane));
}

__global__ __launch_bounds__(64) void crf_kernel(
    const float* __restrict__ frames, const float* __restrict__ trans,
    float* __restrict__ dout)
{
    __shared__ float fr[512 * NT + 16];            // +pad for prefetch-past-end
    __shared__ unsigned char bpl[SEQ * NT];        // 36864 B backpointers
    const int t = threadIdx.x;
    const int tc = (t < NT) ? t : 0;               // clamped lane for fr reads

    float trow[NT];
    #pragma unroll
    for (int i = 0; i < NT; ++i) trow[i] = 0.f;
    if (t < NT) {
        #pragma unroll
        for (int i = 0; i < NT; ++i) trow[i] = trans[i * NT + t];
    }
    float alpha = (t == TSTART) ? 0.f : NEGV;      // lane t holds alpha[t]

    for (int chunk = 0; chunk < 8; ++chunk) {
        // float4 staging (frames base + 18432*chunk both 16B-aligned)
        const float4* src4 = (const float4*)(frames + chunk * 512 * NT);
        float4* dst4 = (float4*)fr;
        for (int idx = t; idx < 512 * NT / 4; idx += 64)
            dst4[idx] = src4[idx];
        __syncthreads();   // single wave: cheap

        float frv = fr[tc];                        // prefetch seed for sl=0
        #pragma unroll 4
        for (int sl = 0; sl < 512; ++sl) {
            const int s = chunk * 512 + sl;
            float frn = fr[(sl + 1) * NT + tc];    // prefetch next (off-chain)
            float v[NT];
            #pragma unroll
            for (int i = 0; i < NT; ++i)
                v[i] = bcast_lane(alpha, i) + trow[i]; // readlane broadcast
            // exact max via 3-way nesting (-> v_max3_f32; max is exact
            // under any association)
            float ma = fmaxf(fmaxf(v[0], v[1]), v[2]);
            float mb = fmaxf(fmaxf(v[3], v[4]), v[5]);
            float mc = fmaxf(fmaxf(v[6], v[7]), v[8]);
            float mx = fmaxf(fmaxf(ma, mb), mc);
            float fm = frv + mx;                   // pre-add while exps run
            // first-match argmax (== jnp.argmax first-occurrence semantics);
            // off the alpha critical path
            int am = 8;
            #pragma unroll
            for (int i = 7; i >= 0; --i)
                if (v[i] == mx) am = i;
            float sum = 0.f;                       // LINEAR order (bit-exact)
            #pragma unroll
            for (int i = 0; i < NT; ++i) sum += __expf(v[i] - mx);
            float anew = fm + __logf(sum);
            if (t < NT) {
                bpl[s * NT + t] = (unsigned char)am;
                alpha = anew;
            }
            frv = frn;
        }
        __syncthreads();
    }

    // final: fin[j] = alpha[j] + trans[j, STOP]; gather with ALL lanes active
    float fin = NEGV;
    if (t < NT) fin = alpha + trans[t * NT + TSTOP];
    float f[NT];
    #pragma unroll
    for (int j = 0; j < NT; ++j) f[j] = bcast_lane(fin, j);

    // best/score computed by ALL lanes (identical values, same op order);
    // only lane 0 stores the score.
    float mx2 = f[0];
    int best = 0;
    #pragma unroll
    for (int j = 1; j < NT; ++j)
        if (f[j] > mx2) { mx2 = f[j]; best = j; }
    float sum2 = 0.f;
    #pragma unroll
    for (int j = 0; j < NT; ++j) sum2 += __expf(f[j] - mx2);
    if (t == 0) dout[0] = mx2 + __logf(sum2);

    // ---- parallel backtrack (round-7, verified) ---------------------------
    // tag chain: t_{4095}=best; t_s = bpl[(s+1)*NT + t_{s+1}].
    // Lane l owns map rows u = l*64+1 .. l*64+64 (lane 63 row i=63 =
    // identity pad). Rows packed as 9 nibbles. Integer-exact.
    unsigned rlo[64], rhi[64];
    {
        const int base_u = t * 64 + 1;
        #pragma unroll
        for (int i = 0; i < 64; ++i) {
            unsigned lo, hi;
            if (t == 63 && i == 63) {
                lo = 0x76543210u; hi = 8u;           // identity map
            } else {
                const int u = base_u + i;
                lo = 0;
                #pragma unroll
                for (int k = 0; k < 8; ++k)
                    lo |= ((unsigned)bpl[u * NT + k]) << (4 * k);
                hi = (unsigned)bpl[u * NT + 8];
            }
            rlo[i] = lo; rhi[i] = hi;
        }
    }

    // compose segment map G_l = row_0 o row_1 o ... o row_63
    unsigned gm[NT];
    #pragma unroll
    for (int k = 0; k < NT; ++k) gm[k] = (unsigned)k;
    #pragma unroll
    for (int i = 63; i >= 0; --i) {
        #pragma unroll
        for (int k = 0; k < NT; ++k)
            gm[k] = nib_ext(rlo[i], rhi[i], gm[k]);
    }
    unsigned Glo = 0, Ghi = gm[8] & 15u;
    #pragma unroll
    for (int k = 0; k < 8; ++k) Glo |= gm[k] << (4 * k);

    // boundary scan: lane l captures its replay seed E before G_l applies.
    int cur = best;
    int E   = best;
    for (int lx = 63; lx >= 0; --lx) {
        unsigned glo = __shfl(Glo, lx);
        unsigned ghi = __shfl(Ghi, lx);
        if (t == lx) E = cur;
        cur = (int)nib_ext(glo, ghi, (unsigned)cur);
    }

    // replay: lane l writes tags for s = l*64+63 down to l*64.
    unsigned tg = (unsigned)E;
    #pragma unroll
    for (int i = 63; i >= 0; --i) {
        tg = nib_ext(rlo[i], rhi[i], tg);
        dout[1 + t * 64 + i] = (float)tg;
    }
}

// ---------------------------------------------------------------------------
extern "C" void kernel_launch(void* const* d_in, const int* in_sizes, int n_in,
                              void* d_out, int out_size, void* d_ws, size_t ws_size,
                              hipStream_t stream)
{
    const int*   sentence = (const int*)  d_in[0];
    const float* embed    = (const float*)d_in[1];
    const float* w_ih_f   = (const float*)d_in[2];
    const float* w_hh_f   = (const float*)d_in[3];
    const float* b_ih_f   = (const float*)d_in[4];
    const float* b_hh_f   = (const float*)d_in[5];
    const float* w_ih_b   = (const float*)d_in[6];
    const float* w_hh_b   = (const float*)d_in[7];
    const float* b_ih_b   = (const float*)d_in[8];
    const float* b_hh_b   = (const float*)d_in[9];
    const float* h0       = (const float*)d_in[10];
    const float* c0       = (const float*)d_in[11];
    const float* W_out    = (const float*)d_in[12];
    const float* b_out    = (const float*)d_in[13];
    const float* trans    = (const float*)d_in[14];

    float* out = (float*)d_out;
    char*  ws  = (char*)d_ws;

    float* xg_f   = (float*)(ws + WS_XG_F);
    float* xg_b   = (float*)(ws + WS_XG_B);
    float* hf     = (float*)(ws + WS_HF);
    float* hb     = (float*)(ws + WS_HB);
    float* frames = (float*)(ws + WS_FRAMES);

    // Poison of hf/hb is fused into xgate_kernel (round-11).
    xgate_kernel<<<dim3(256, 2), 256, 0, stream>>>(
        sentence, embed, w_ih_f, b_ih_f, b_hh_f, w_ih_b, b_ih_b, b_hh_b,
        xg_f, xg_b, hf);

    lstm_kernel<<<16, 256, 0, stream>>>(
        xg_f, xg_b, w_hh_f, w_hh_b, h0, c0, hf, hb);

    frames_kernel<<<(SEQ * NT + 255) / 256, 256, 0, stream>>>(
        hf, hb, W_out, b_out, frames);

    crf_kernel<<<1, 64, 0, stream>>>(frames, trans, out);
}